// Round 1
// baseline (580.967 us; speedup 1.0000x reference)
//
#include <hip/hip_runtime.h>
#include <math.h>

#define Bn 16
#define Tn 2048
#define Wn 10
constexpr float PI_F = 3.14159265358979323846f;

// ---- output offsets (floats) ----
constexpr size_t O_EMB   = 0;
constexpr size_t O_PSPEC = (size_t)Bn*Tn*256;            // 8388608
constexpr size_t O_PPAR  = O_PSPEC + (size_t)Bn*Tn*20;   // 9043968
constexpr size_t O_TSPEC = O_PPAR + 2*Bn;                // 9044000
constexpr size_t O_TPAR  = O_TSPEC + (size_t)Bn*Tn*20;   // 9699360

// ---- workspace offsets (floats) ----
constexpr size_t WS_WT1 = 0;
constexpr size_t WS_WT2 = WS_WT1 + 3*256*256;
constexpr size_t WS_H1  = WS_WT2 + 3*256*256;
constexpr size_t WS_MS  = WS_H1 + (size_t)Bn*Tn*256;
constexpr size_t WS_X   = WS_MS + 2*Bn;
constexpr size_t WS_Z   = WS_X + (size_t)Bn*1024*2;
constexpr size_t WS_P2  = WS_Z + (size_t)Bn*1024*20;
constexpr size_t WS_WP  = WS_P2 + (size_t)Bn*Tn*2;       // 4 * Bn*Tn*20 partials

// ---------------- weight transpose: w[o][i][k] -> wT[k][i][o] ----------------
__global__ void k_transpose_w(const float* __restrict__ w, float* __restrict__ wT){
  int idx = blockIdx.x*256 + threadIdx.x;            // 3*256*256
  int o = idx & 255, i = (idx>>8)&255, k = idx>>16;
  wT[idx] = w[(o*256 + i)*3 + k];
}

// ---------------- per-batch stats: means/stds + target_params ----------------
__global__ void k_stats(const float* __restrict__ target, const int* __restrict__ mel,
                        float* __restrict__ msbuf, float* __restrict__ tpar){
  __shared__ float red[256];
  __shared__ float mean_sh;
  int b = blockIdx.x, tid = threadIdx.x;
  const float* tg = target + (size_t)b*Tn;
  int len = mel[b];
  float lenf = (float)len;
  float s = 0.f;
  for (int t=tid; t<Tn; t+=256) s += tg[t];
  red[tid]=s; __syncthreads();
  for (int off=128; off; off>>=1){ if(tid<off) red[tid]+=red[tid+off]; __syncthreads(); }
  if (tid==0) mean_sh = red[0]/lenf;
  __syncthreads();
  float mean = mean_sh;
  float s2 = 0.f;
  for (int t=tid; t<Tn; t+=256){ float d = (t<len)?(tg[t]-mean):0.f; s2 += d*d; }
  red[tid]=s2; __syncthreads();
  for (int off=128; off; off>>=1){ if(tid<off) red[tid]+=red[tid+off]; __syncthreads(); }
  if (tid==0){
    float stdv = sqrtf(red[0]/(lenf-1.f));
    msbuf[2*b]=mean; msbuf[2*b+1]=stdv;
    tpar[2*b]=mean;  tpar[2*b+1]=stdv;
  }
}

// ---------------- forward DFT of c_norm: X[b][k], k=0..1023 ----------------
__global__ void k_fwd_dft(const float* __restrict__ target, const int* __restrict__ mel,
                          const float* __restrict__ msbuf, float* __restrict__ X){
  __shared__ float cbuf[Tn];
  __shared__ float2 tw[Tn];
  int b = blockIdx.x >> 6, kc = blockIdx.x & 63, tid = threadIdx.x;
  int len = mel[b];
  float mean = msbuf[2*b];
  float istd = 1.f / msbuf[2*b+1];
  for (int n=tid; n<Tn; n+=256){
    float sn, cs;
    sincosf((2.f*PI_F/Tn)*n, &sn, &cs);
    tw[n] = make_float2(cs, sn);
    cbuf[n] = (n<len) ? (target[(size_t)b*Tn+n]-mean)*istd : 0.f;
  }
  __syncthreads();
  int k  = (kc<<4) | (tid>>4);
  int tl = tid & 15;
  float xr=0.f, xi=0.f;
  for (int t=tl; t<Tn; t+=16){
    int n = (k*t) & (Tn-1);
    float2 w = tw[n];
    float cv = cbuf[t];
    xr += cv*w.x;     // e^{-i th}: (cos, -sin)
    xi -= cv*w.y;
  }
  #pragma unroll
  for (int m=1; m<16; m<<=1){ xr += __shfl_xor(xr,m); xi += __shfl_xor(xi,m); }
  if (tl==0){ X[2*(b*1024+k)] = xr; X[2*(b*1024+k)+1] = xi; }
}

// ---------------- Z[b][k][s*2+{re,im}] = X * psi_hat / T ----------------
__global__ void k_zmul(const float* __restrict__ X, float* __restrict__ Z){
  int idx = blockIdx.x*256 + threadIdx.x;  // Bn*1024
  int k = idx & 1023;
  float xr = X[2*idx], xi = X[2*idx+1];
  float omega = (2.f*PI_F/Tn)*k;
  const float pref = 0.7511255444649425f;  // pi^-0.25
  const float invT = 1.f/Tn;
  float* zp = Z + (size_t)idx*20;
  #pragma unroll
  for (int s=0; s<Wn; s++){
    float sc = expf(0.4f*(float)s);
    float arg = sc*omega - 6.0f;
    float psi = (k>0) ? pref*sqrtf(2.f*PI_F*sc)*expf(-0.5f*arg*arg)*invT : 0.f;
    zp[2*s]   = xr*psi;
    zp[2*s+1] = xi*psi;
  }
}

// ---------------- inverse DFT partials over k-chunks ----------------
__global__ void k_inv_dft(const float* __restrict__ Z, float* __restrict__ Wp){
  __shared__ float2 tw[Tn];
  __shared__ __align__(16) float zc[256*20];
  int tt = blockIdx.x, kc = blockIdx.y, b = blockIdx.z, tid = threadIdx.x;
  for (int n=tid; n<Tn; n+=256){
    float sn, cs;
    sincosf((2.f*PI_F/Tn)*n, &sn, &cs);
    tw[n] = make_float2(cs, sn);
  }
  const float* zsrc = Z + ((size_t)b*1024 + kc*256)*20;
  for (int j=tid; j<256*20; j+=256) zc[j] = zsrc[j];
  __syncthreads();
  int t = tt*256 + tid;
  float wr[Wn], wi[Wn];
  #pragma unroll
  for (int s=0;s<Wn;s++){ wr[s]=0.f; wi[s]=0.f; }
  int kbase = kc*256;
  for (int kk=0; kk<256; kk++){
    int n = ((kbase+kk)*t) & (Tn-1);
    float2 w = tw[n];
    const float4* z4 = (const float4*)(zc + kk*20);
    #pragma unroll
    for (int q=0;q<5;q++){
      float4 z = z4[q];
      wr[2*q]   += z.x*w.x - z.y*w.y;   // e^{+i th}
      wi[2*q]   += z.x*w.y + z.y*w.x;
      wr[2*q+1] += z.z*w.x - z.w*w.y;
      wi[2*q+1] += z.z*w.y + z.w*w.x;
    }
  }
  float* dst = Wp + (((size_t)kc*Bn + b)*Tn + t)*20;
  #pragma unroll
  for (int s=0;s<Wn;s++){ dst[s] = wr[s]; dst[Wn+s] = wi[s]; }
}

// ---------------- combine partials + mask -> target_spec ----------------
__global__ void k_combine(const float* __restrict__ Wp, const int* __restrict__ mel,
                          float* __restrict__ tspec){
  int idx = blockIdx.x*256 + threadIdx.x;  // Bn*Tn*20
  int bt = idx / 20;
  int t = bt & (Tn-1), b = bt >> 11;
  float s = 0.f;
  #pragma unroll
  for (int kc=0; kc<4; kc++) s += Wp[(size_t)kc*Bn*Tn*20 + idx];
  tspec[idx] = (t < mel[b]) ? s : 0.f;
}

// ---------------- conv1d(k=3) + LN + relu (+ fused linear in stage 2) --------
template<int STAGE>
__global__ void k_conv_ln(const float* __restrict__ in, const float* __restrict__ wT,
                          const float* __restrict__ cb, const float* __restrict__ g,
                          const float* __restrict__ be, float* __restrict__ h_out,
                          const float* __restrict__ lw, const float* __restrict__ lb,
                          const int* __restrict__ mel, float* __restrict__ pspec,
                          float* __restrict__ p2){
  __shared__ float smem[34*257];    // x tile (34 rows), later aliased as y tile (32 rows)
  int bx = blockIdx.x, b = blockIdx.y, tid = threadIdx.x;
  int tbase = bx*32;
  for (int rc = tid; rc < 34*256; rc += 256){
    int r = rc >> 8, c = rc & 255;
    int t = tbase + r - 1;
    smem[r*257 + c] = ((unsigned)t < (unsigned)Tn) ? in[((size_t)b*Tn + t)*256 + c] : 0.f;
  }
  __syncthreads();
  int to = tid & 63, tt = tid >> 6;
  int o0 = to*4;
  float acc[8][4];
  #pragma unroll
  for (int jj=0;jj<8;jj++){ acc[jj][0]=0.f;acc[jj][1]=0.f;acc[jj][2]=0.f;acc[jj][3]=0.f; }
  for (int i=0;i<256;i++){
    float xv[10];
    #pragma unroll
    for (int j=0;j<10;j++) xv[j] = smem[(tt*8+j)*257 + i];
    #pragma unroll
    for (int k=0;k<3;k++){
      float4 wv = *(const float4*)(wT + ((size_t)(k<<8)+i)*256 + o0);
      #pragma unroll
      for (int jj=0;jj<8;jj++){
        acc[jj][0] += xv[jj+k]*wv.x;
        acc[jj][1] += xv[jj+k]*wv.y;
        acc[jj][2] += xv[jj+k]*wv.z;
        acc[jj][3] += xv[jj+k]*wv.w;
      }
    }
  }
  __syncthreads();     // all x reads done; alias smem as y tile
  float4 bias = *(const float4*)(cb + o0);
  #pragma unroll
  for (int jj=0;jj<8;jj++){
    float* yrow = smem + (tt*8+jj)*257 + o0;
    yrow[0]=acc[jj][0]+bias.x; yrow[1]=acc[jj][1]+bias.y;
    yrow[2]=acc[jj][2]+bias.z; yrow[3]=acc[jj][3]+bias.w;
  }
  __syncthreads();
  int lane = tid & 63;
  for (int rr=0; rr<8; rr++){
    int row = tt*8 + rr;               // wave tt owns rows tt*8..tt*8+7
    float v[4];
    #pragma unroll
    for (int q=0;q<4;q++) v[q] = smem[row*257 + lane + 64*q];
    float s = v[0]+v[1]+v[2]+v[3];
    #pragma unroll
    for (int m=1;m<64;m<<=1) s += __shfl_xor(s, m);
    float mean = s * (1.f/256.f);
    float d[4]; float vs = 0.f;
    #pragma unroll
    for (int q=0;q<4;q++){ d[q]=v[q]-mean; vs += d[q]*d[q]; }
    #pragma unroll
    for (int m=1;m<64;m<<=1) vs += __shfl_xor(vs, m);
    float rstd = rsqrtf(vs*(1.f/256.f) + 1e-5f);
    #pragma unroll
    for (int q=0;q<4;q++){
      int o = lane + 64*q;
      float h = fmaxf(d[q]*rstd*g[o] + be[o], 0.f);
      if (STAGE==1){
        h_out[((size_t)b*Tn + tbase + row)*256 + o] = h;
      } else {
        smem[row*257 + o] = h;
      }
    }
  }
  if (STAGE==2){
    __syncthreads();
    int len = mel[b];
    for (int task = tid; task < 32*22; task += 256){
      int r = task / 22, o = task - r*22;
      const float* hrow = smem + r*257;
      const float* wrow = lw + o*256;
      float sum = lb[o];
      for (int f=0; f<256; f++) sum += hrow[f]*wrow[f];
      int t = tbase + r;
      if (o < 20) pspec[((size_t)b*Tn + t)*20 + o] = (t<len) ? sum : 0.f;
      else        p2[((size_t)b*Tn + t)*2 + (o-20)] = sum;   // unmasked
    }
  }
}

// ---------------- predictor_params: mean over t of p2 ----------------
__global__ void k_pparams(const float* __restrict__ p2, float* __restrict__ ppar){
  __shared__ float r0[256], r1[256];
  int b = blockIdx.x, tid = threadIdx.x;
  float s0=0.f, s1=0.f;
  for (int t=tid; t<Tn; t+=256){
    s0 += p2[((size_t)b*Tn+t)*2];
    s1 += p2[((size_t)b*Tn+t)*2+1];
  }
  r0[tid]=s0; r1[tid]=s1; __syncthreads();
  for (int off=128; off; off>>=1){ if(tid<off){r0[tid]+=r0[tid+off]; r1[tid]+=r1[tid+off];} __syncthreads(); }
  if (tid==0){ ppar[2*b] = r0[0]*(1.f/Tn); ppar[2*b+1] = r1[0]*(1.f/Tn); }
}

// ---------------- quantize + embedding gather ----------------
__global__ void k_embed(const float* __restrict__ target, const float* __restrict__ alpha,
                        const int* __restrict__ mel, const float* __restrict__ emb,
                        float* __restrict__ out){
  int row  = blockIdx.x*4 + (threadIdx.x>>6);   // b*Tn + t
  int lane = threadIdx.x & 63;
  int b = row >> 11, t = row & (Tn-1);
  int qid = 0;
  if (t < mel[b]){
    float q = target[row]*alpha[b];
    q = fminf(fmaxf(q, 0.f), 800.f);
    qid = (int)rintf(q/3.125f) + 1;             // round-half-even matches jnp.round
  }
  float4 v = ((const float4*)(emb + (size_t)qid*256))[lane];
  ((float4*)(out + (size_t)row*256))[lane] = v;
}

extern "C" void kernel_launch(void* const* d_in, const int* in_sizes, int n_in,
                              void* d_out, int out_size, void* d_ws, size_t ws_size,
                              hipStream_t stream) {
  const float* x      = (const float*)d_in[0];
  const float* alpha  = (const float*)d_in[1];
  const float* target = (const float*)d_in[2];
  const int*   mel    = (const int*)  d_in[3];
  const float* w1     = (const float*)d_in[4];
  const float* b1     = (const float*)d_in[5];
  const float* g1     = (const float*)d_in[6];
  const float* be1    = (const float*)d_in[7];
  const float* w2     = (const float*)d_in[8];
  const float* b2     = (const float*)d_in[9];
  const float* g2     = (const float*)d_in[10];
  const float* be2    = (const float*)d_in[11];
  const float* lw     = (const float*)d_in[12];
  const float* lb     = (const float*)d_in[13];
  const float* emb    = (const float*)d_in[14];
  float* out = (float*)d_out;
  float* ws  = (float*)d_ws;

  k_transpose_w<<<768, 256, 0, stream>>>(w1, ws + WS_WT1);
  k_transpose_w<<<768, 256, 0, stream>>>(w2, ws + WS_WT2);
  k_stats<<<Bn, 256, 0, stream>>>(target, mel, ws + WS_MS, out + O_TPAR);
  k_fwd_dft<<<Bn*64, 256, 0, stream>>>(target, mel, ws + WS_MS, ws + WS_X);
  k_zmul<<<Bn*1024/256, 256, 0, stream>>>(ws + WS_X, ws + WS_Z);
  k_inv_dft<<<dim3(Tn/256, 4, Bn), 256, 0, stream>>>(ws + WS_Z, ws + WS_WP);
  k_combine<<<Bn*Tn*20/256, 256, 0, stream>>>(ws + WS_WP, mel, out + O_TSPEC);
  k_conv_ln<1><<<dim3(Tn/32, Bn), 256, 0, stream>>>(x, ws + WS_WT1, b1, g1, be1,
                                                    ws + WS_H1, nullptr, nullptr,
                                                    mel, nullptr, nullptr);
  k_conv_ln<2><<<dim3(Tn/32, Bn), 256, 0, stream>>>(ws + WS_H1, ws + WS_WT2, b2, g2, be2,
                                                    nullptr, lw, lb,
                                                    mel, out + O_PSPEC, ws + WS_P2);
  k_pparams<<<Bn, 256, 0, stream>>>(ws + WS_P2, out + O_PPAR);
  k_embed<<<Bn*Tn/4, 256, 0, stream>>>(target, alpha, mel, emb, out + O_EMB);
}

// Round 2
// 282.457 us; speedup vs baseline: 2.0568x; 2.0568x over previous
//
#include <hip/hip_runtime.h>
#include <hip/hip_bf16.h>
#include <math.h>

#define Bn 16
#define Tn 2048
#define Wn 10
constexpr float PI_F = 3.14159265358979323846f;

typedef __bf16 bf16x8 __attribute__((ext_vector_type(8)));
typedef float  f32x4  __attribute__((ext_vector_type(4)));

// ---- output offsets (floats) ----
constexpr size_t O_EMB   = 0;
constexpr size_t O_PSPEC = (size_t)Bn*Tn*256;            // 8388608
constexpr size_t O_PPAR  = O_PSPEC + (size_t)Bn*Tn*20;   // 9043968
constexpr size_t O_TSPEC = O_PPAR + 2*Bn;                // 9044000
constexpr size_t O_TPAR  = O_TSPEC + (size_t)Bn*Tn*20;   // 9699360

// ---- workspace BYTE offsets ----
constexpr size_t OB_WB1 = 0;                              // 768*256 bf16
constexpr size_t OB_WB2 = OB_WB1 + 393216;
constexpr size_t OB_H1  = OB_WB2 + 393216;                // B*T*256 bf16
constexpr size_t OB_MS  = OB_H1 + 16777216;               // 32 f32
constexpr size_t OB_X   = OB_MS + 128;                    // B*1024*2 f32
constexpr size_t OB_Z   = OB_X + 131072;                  // B*1024*20 f32
constexpr size_t OB_P2  = OB_Z + 1310720;                 // B*T*2 f32
constexpr size_t OB_WP  = OB_P2 + 262144;                 // 4*B*T*20 f32

// ------------- weight prep: w[o][i][k3] fp32 -> wB[o][k3*256+i] bf16 -------------
__global__ void k_prep_w(const float* __restrict__ w1, const float* __restrict__ w2,
                         __bf16* __restrict__ wb1, __bf16* __restrict__ wb2){
  int idx = blockIdx.x*256 + threadIdx.x;     // 2 * 196608
  const float* w = w1; __bf16* wb = wb1;
  if (idx >= 196608){ idx -= 196608; w = w2; wb = wb2; }
  int i = idx & 255;
  int r = idx >> 8;              // o*3 + k3
  int k3 = r % 3, o = r / 3;
  wb[idx] = (__bf16)w[((size_t)o*256 + i)*3 + k3];
}

// ---------------- per-batch stats: means/stds + target_params ----------------
__global__ void k_stats(const float* __restrict__ target, const int* __restrict__ mel,
                        float* __restrict__ msbuf, float* __restrict__ tpar){
  __shared__ float red[256];
  __shared__ float mean_sh;
  int b = blockIdx.x, tid = threadIdx.x;
  const float* tg = target + (size_t)b*Tn;
  int len = mel[b];
  float lenf = (float)len;
  float s = 0.f;
  for (int t=tid; t<Tn; t+=256) s += tg[t];
  red[tid]=s; __syncthreads();
  for (int off=128; off; off>>=1){ if(tid<off) red[tid]+=red[tid+off]; __syncthreads(); }
  if (tid==0) mean_sh = red[0]/lenf;
  __syncthreads();
  float mean = mean_sh;
  float s2 = 0.f;
  for (int t=tid; t<Tn; t+=256){ float d = (t<len)?(tg[t]-mean):0.f; s2 += d*d; }
  red[tid]=s2; __syncthreads();
  for (int off=128; off; off>>=1){ if(tid<off) red[tid]+=red[tid+off]; __syncthreads(); }
  if (tid==0){
    float stdv = sqrtf(red[0]/(lenf-1.f));
    msbuf[2*b]=mean; msbuf[2*b+1]=stdv;
    tpar[2*b]=mean;  tpar[2*b+1]=stdv;
  }
}

// ---------------- forward DFT of c_norm: X[b][k], k=0..1023 ----------------
__global__ void k_fwd_dft(const float* __restrict__ target, const int* __restrict__ mel,
                          const float* __restrict__ msbuf, float* __restrict__ X){
  __shared__ float cbuf[Tn];
  __shared__ float2 tw[Tn];
  int b = blockIdx.x >> 6, kc = blockIdx.x & 63, tid = threadIdx.x;
  int len = mel[b];
  float mean = msbuf[2*b];
  float istd = 1.f / msbuf[2*b+1];
  for (int n=tid; n<Tn; n+=256){
    float sn, cs;
    sincosf((2.f*PI_F/Tn)*n, &sn, &cs);
    tw[n] = make_float2(cs, sn);
    cbuf[n] = (n<len) ? (target[(size_t)b*Tn+n]-mean)*istd : 0.f;
  }
  __syncthreads();
  int k  = (kc<<4) | (tid>>4);
  int tl = tid & 15;
  float xr=0.f, xi=0.f;
  for (int t=tl; t<Tn; t+=16){
    int n = (k*t) & (Tn-1);
    float2 w = tw[n];
    float cv = cbuf[t];
    xr += cv*w.x;     // e^{-i th}: (cos, -sin)
    xi -= cv*w.y;
  }
  #pragma unroll
  for (int m=1; m<16; m<<=1){ xr += __shfl_xor(xr,m); xi += __shfl_xor(xi,m); }
  if (tl==0){ X[2*(b*1024+k)] = xr; X[2*(b*1024+k)+1] = xi; }
}

// ---------------- Z[b][k][s*2+{re,im}] = X * psi_hat / T ----------------
__global__ void k_zmul(const float* __restrict__ X, float* __restrict__ Z){
  int idx = blockIdx.x*256 + threadIdx.x;  // Bn*1024
  int k = idx & 1023;
  float xr = X[2*idx], xi = X[2*idx+1];
  float omega = (2.f*PI_F/Tn)*k;
  const float pref = 0.7511255444649425f;  // pi^-0.25
  const float invT = 1.f/Tn;
  float* zp = Z + (size_t)idx*20;
  #pragma unroll
  for (int s=0; s<Wn; s++){
    float sc = expf(0.4f*(float)s);
    float arg = sc*omega - 6.0f;
    float psi = (k>0) ? pref*sqrtf(2.f*PI_F*sc)*expf(-0.5f*arg*arg)*invT : 0.f;
    zp[2*s]   = xr*psi;
    zp[2*s+1] = xi*psi;
  }
}

// ---------------- inverse DFT partials over k-chunks ----------------
__global__ void k_inv_dft(const float* __restrict__ Z, float* __restrict__ Wp){
  __shared__ float2 tw[Tn];
  __shared__ __align__(16) float zc[256*20];
  int tt = blockIdx.x, kc = blockIdx.y, b = blockIdx.z, tid = threadIdx.x;
  for (int n=tid; n<Tn; n+=256){
    float sn, cs;
    sincosf((2.f*PI_F/Tn)*n, &sn, &cs);
    tw[n] = make_float2(cs, sn);
  }
  const float* zsrc = Z + ((size_t)b*1024 + kc*256)*20;
  for (int j=tid; j<256*20; j+=256) zc[j] = zsrc[j];
  __syncthreads();
  int t = tt*256 + tid;
  float wr[Wn], wi[Wn];
  #pragma unroll
  for (int s=0;s<Wn;s++){ wr[s]=0.f; wi[s]=0.f; }
  int kbase = kc*256;
  for (int kk=0; kk<256; kk++){
    int n = ((kbase+kk)*t) & (Tn-1);
    float2 w = tw[n];
    const float4* z4 = (const float4*)(zc + kk*20);
    #pragma unroll
    for (int q=0;q<5;q++){
      float4 z = z4[q];
      wr[2*q]   += z.x*w.x - z.y*w.y;   // e^{+i th}
      wi[2*q]   += z.x*w.y + z.y*w.x;
      wr[2*q+1] += z.z*w.x - z.w*w.y;
      wi[2*q+1] += z.z*w.y + z.w*w.x;
    }
  }
  float* dst = Wp + (((size_t)kc*Bn + b)*Tn + t)*20;
  #pragma unroll
  for (int s=0;s<Wn;s++){ dst[s] = wr[s]; dst[Wn+s] = wi[s]; }
}

// ---------------- combine partials + mask -> target_spec ----------------
__global__ void k_combine(const float* __restrict__ Wp, const int* __restrict__ mel,
                          float* __restrict__ tspec){
  int idx = blockIdx.x*256 + threadIdx.x;  // Bn*Tn*20
  int bt = idx / 20;
  int t = bt & (Tn-1), b = bt >> 11;
  float s = 0.f;
  #pragma unroll
  for (int kc=0; kc<4; kc++) s += Wp[(size_t)kc*Bn*Tn*20 + idx];
  tspec[idx] = (t < mel[b]) ? s : 0.f;
}

// ======== conv1d(k=3) as bf16 MFMA GEMM + fused LN/relu (+ linear, stage2) ========
// Block: 256 thr (4 waves), tile = 64 t-rows x 256 out-ch, K = 768 (k3-major).
// LDS: A-tile 66 rows x 256 bf16, XOR-swizzled (slot ^= row&7); aliased by
//      y-tile 64 x 256 f32 after the GEMM.  Exactly 64 KiB static.
template<int STAGE>
__global__ __launch_bounds__(256) void k_conv_mfma(
    const void* __restrict__ in_v, const __bf16* __restrict__ wB,
    const float* __restrict__ cb, const float* __restrict__ g, const float* __restrict__ be,
    __bf16* __restrict__ h_out,
    const float* __restrict__ lw, const float* __restrict__ lb,
    const int* __restrict__ mel, float* __restrict__ pspec, float* __restrict__ p2)
{
  __shared__ float smemf[64*256];            // 65536 B
  char* smemb = (char*)smemf;                // A-tile view: row*512 + slot*16 (swizzled)
  int tid = threadIdx.x, b = blockIdx.y, tbase = blockIdx.x*64;

  // ---- stage A (66 rows incl. halo), convert to bf16, swizzled 16B granules ----
  for (int gi = tid; gi < 66*32; gi += 256){
    int r = gi >> 5, s = gi & 31;
    int t = tbase + r - 1;
    bf16x8 val;
    if ((unsigned)t < (unsigned)Tn){
      if (STAGE==1){
        const float4* src = (const float4*)((const float*)in_v + ((size_t)b*Tn + t)*256 + s*8);
        float4 a0 = src[0], a1 = src[1];
        val[0]=(__bf16)a0.x; val[1]=(__bf16)a0.y; val[2]=(__bf16)a0.z; val[3]=(__bf16)a0.w;
        val[4]=(__bf16)a1.x; val[5]=(__bf16)a1.y; val[6]=(__bf16)a1.z; val[7]=(__bf16)a1.w;
      } else {
        val = *(const bf16x8*)((const __bf16*)in_v + ((size_t)b*Tn + t)*256 + s*8);
      }
    } else {
      #pragma unroll
      for (int j=0;j<8;j++) val[j] = (__bf16)0.f;
    }
    *(bf16x8*)(smemb + r*512 + ((s*16) ^ ((r&7)<<4))) = val;
  }
  __syncthreads();

  // ---- MFMA GEMM: wave w owns n-cols [w*64, w*64+64), all 64 m-rows ----
  int w = tid >> 6, l = tid & 63;
  int ow = w*64;
  int lm = l & 15, lk = l >> 4;
  f32x4 acc[4][4];
  #pragma unroll
  for (int mf=0; mf<4; mf++)
    #pragma unroll
    for (int nf=0; nf<4; nf++) acc[mf][nf] = (f32x4){0.f,0.f,0.f,0.f};

  const __bf16* bp[4];
  #pragma unroll
  for (int nf=0; nf<4; nf++) bp[nf] = wB + (size_t)(ow + nf*16 + lm)*768 + lk*8;

  for (int k3=0; k3<3; k3++){
    #pragma unroll
    for (int i0=0; i0<256; i0+=32){
      bf16x8 af[4], bfr[4];
      #pragma unroll
      for (int mf=0; mf<4; mf++){
        int row = mf*16 + lm + k3;
        int off = (i0*2 + lk*16) ^ ((row&7)<<4);
        af[mf] = *(const bf16x8*)(smemb + row*512 + off);
      }
      int kk = k3*256 + i0;
      #pragma unroll
      for (int nf=0; nf<4; nf++) bfr[nf] = *(const bf16x8*)(bp[nf] + kk);
      #pragma unroll
      for (int mf=0; mf<4; mf++)
        #pragma unroll
        for (int nf=0; nf<4; nf++)
          acc[mf][nf] = __builtin_amdgcn_mfma_f32_16x16x32_bf16(af[mf], bfr[nf], acc[mf][nf], 0, 0, 0);
    }
  }
  __syncthreads();   // all A-tile reads complete before aliasing as y-tile

  // ---- epilogue: y = acc + bias into f32 y-tile [64][256] ----
  #pragma unroll
  for (int nf=0; nf<4; nf++){
    int o = ow + nf*16 + lm;
    float bias = cb[o];
    #pragma unroll
    for (int mf=0; mf<4; mf++){
      #pragma unroll
      for (int j=0;j<4;j++){
        int m = mf*16 + lk*4 + j;
        smemf[m*256 + o] = acc[mf][nf][j] + bias;
      }
    }
  }
  __syncthreads();

  // ---- LN + relu: wave w handles rows w*16 .. w*16+15 ----
  float gv[4], bev[4];
  #pragma unroll
  for (int q=0;q<4;q++){ gv[q] = g[l + 64*q]; bev[q] = be[l + 64*q]; }
  for (int rr=0; rr<16; rr++){
    int row = w*16 + rr;
    float v[4];
    #pragma unroll
    for (int q=0;q<4;q++) v[q] = smemf[row*256 + l + 64*q];
    float s = v[0]+v[1]+v[2]+v[3];
    #pragma unroll
    for (int m=1;m<64;m<<=1) s += __shfl_xor(s, m);
    float mean = s * (1.f/256.f);
    float d[4]; float vs = 0.f;
    #pragma unroll
    for (int q=0;q<4;q++){ d[q]=v[q]-mean; vs += d[q]*d[q]; }
    #pragma unroll
    for (int m=1;m<64;m<<=1) vs += __shfl_xor(vs, m);
    float rstd = rsqrtf(vs*(1.f/256.f) + 1e-5f);
    #pragma unroll
    for (int q=0;q<4;q++){
      float h = fmaxf(d[q]*rstd*gv[q] + bev[q], 0.f);
      smemf[row*256 + l + 64*q] = h;
    }
  }
  __syncthreads();

  if (STAGE==1){
    // coalesced bf16 store of h to ws
    for (int gi = tid; gi < 64*32; gi += 256){
      int r = gi >> 5, s = gi & 31;
      const float4* src = (const float4*)(smemf + r*256 + s*8);
      float4 a0 = src[0], a1 = src[1];
      bf16x8 val;
      val[0]=(__bf16)a0.x; val[1]=(__bf16)a0.y; val[2]=(__bf16)a0.z; val[3]=(__bf16)a0.w;
      val[4]=(__bf16)a1.x; val[5]=(__bf16)a1.y; val[6]=(__bf16)a1.z; val[7]=(__bf16)a1.w;
      *(bf16x8*)(h_out + ((size_t)b*Tn + tbase + r)*256 + s*8) = val;
    }
  } else {
    // fused linear 256 -> 22
    int len = mel[b];
    for (int task = tid; task < 64*22; task += 256){
      int r = task / 22, o = task - r*22;
      const float4* h4 = (const float4*)(smemf + r*256);
      const float4* w4 = (const float4*)(lw + o*256);
      float sum = lb[o];
      for (int f=0; f<64; f++){
        float4 hv = h4[f], wv = w4[f];
        sum += hv.x*wv.x + hv.y*wv.y + hv.z*wv.z + hv.w*wv.w;
      }
      int t = tbase + r;
      if (o < 20) pspec[((size_t)b*Tn + t)*20 + o] = (t<len) ? sum : 0.f;
      else        p2[((size_t)b*Tn + t)*2 + (o-20)] = sum;   // unmasked
    }
  }
}

// ---------------- predictor_params: mean over t of p2 ----------------
__global__ void k_pparams(const float* __restrict__ p2, float* __restrict__ ppar){
  __shared__ float r0[256], r1[256];
  int b = blockIdx.x, tid = threadIdx.x;
  float s0=0.f, s1=0.f;
  for (int t=tid; t<Tn; t+=256){
    s0 += p2[((size_t)b*Tn+t)*2];
    s1 += p2[((size_t)b*Tn+t)*2+1];
  }
  r0[tid]=s0; r1[tid]=s1; __syncthreads();
  for (int off=128; off; off>>=1){ if(tid<off){r0[tid]+=r0[tid+off]; r1[tid]+=r1[tid+off];} __syncthreads(); }
  if (tid==0){ ppar[2*b] = r0[0]*(1.f/Tn); ppar[2*b+1] = r1[0]*(1.f/Tn); }
}

// ---------------- quantize + embedding gather ----------------
__global__ void k_embed(const float* __restrict__ target, const float* __restrict__ alpha,
                        const int* __restrict__ mel, const float* __restrict__ emb,
                        float* __restrict__ out){
  int row  = blockIdx.x*4 + (threadIdx.x>>6);   // b*Tn + t
  int lane = threadIdx.x & 63;
  int b = row >> 11, t = row & (Tn-1);
  int qid = 0;
  if (t < mel[b]){
    float q = target[row]*alpha[b];
    q = fminf(fmaxf(q, 0.f), 800.f);
    qid = (int)rintf(q/3.125f) + 1;             // round-half-even matches jnp.round
  }
  float4 v = ((const float4*)(emb + (size_t)qid*256))[lane];
  ((float4*)(out + (size_t)row*256))[lane] = v;
}

extern "C" void kernel_launch(void* const* d_in, const int* in_sizes, int n_in,
                              void* d_out, int out_size, void* d_ws, size_t ws_size,
                              hipStream_t stream) {
  const float* x      = (const float*)d_in[0];
  const float* alpha  = (const float*)d_in[1];
  const float* target = (const float*)d_in[2];
  const int*   mel    = (const int*)  d_in[3];
  const float* w1     = (const float*)d_in[4];
  const float* b1     = (const float*)d_in[5];
  const float* g1     = (const float*)d_in[6];
  const float* be1    = (const float*)d_in[7];
  const float* w2     = (const float*)d_in[8];
  const float* b2     = (const float*)d_in[9];
  const float* g2     = (const float*)d_in[10];
  const float* be2    = (const float*)d_in[11];
  const float* lw     = (const float*)d_in[12];
  const float* lb     = (const float*)d_in[13];
  const float* emb    = (const float*)d_in[14];
  float* out = (float*)d_out;
  char*  wsb = (char*)d_ws;

  __bf16* wb1 = (__bf16*)(wsb + OB_WB1);
  __bf16* wb2 = (__bf16*)(wsb + OB_WB2);
  __bf16* h1  = (__bf16*)(wsb + OB_H1);
  float*  ms  = (float*)(wsb + OB_MS);
  float*  X   = (float*)(wsb + OB_X);
  float*  Z   = (float*)(wsb + OB_Z);
  float*  p2  = (float*)(wsb + OB_P2);
  float*  Wp  = (float*)(wsb + OB_WP);

  k_prep_w<<<1536, 256, 0, stream>>>(w1, w2, wb1, wb2);
  k_stats<<<Bn, 256, 0, stream>>>(target, mel, ms, out + O_TPAR);
  k_fwd_dft<<<Bn*64, 256, 0, stream>>>(target, mel, ms, X);
  k_zmul<<<Bn*1024/256, 256, 0, stream>>>(X, Z);
  k_inv_dft<<<dim3(Tn/256, 4, Bn), 256, 0, stream>>>(Z, Wp);
  k_combine<<<Bn*Tn*20/256, 256, 0, stream>>>(Wp, mel, out + O_TSPEC);
  k_conv_mfma<1><<<dim3(Tn/64, Bn), 256, 0, stream>>>(x, wb1, b1, g1, be1,
                                                      h1, nullptr, nullptr,
                                                      mel, nullptr, nullptr);
  k_conv_mfma<2><<<dim3(Tn/64, Bn), 256, 0, stream>>>(h1, wb2, b2, g2, be2,
                                                      nullptr, lw, lb,
                                                      mel, out + O_PSPEC, p2);
  k_pparams<<<Bn, 256, 0, stream>>>(p2, out + O_PPAR);
  k_embed<<<Bn*Tn/4, 256, 0, stream>>>(target, alpha, mel, emb, out + O_EMB);
}